// Round 6
// baseline (136.005 us; speedup 1.0000x reference)
//
#include <hip/hip_runtime.h>

#define B_ 8
#define H_ 128
#define W_ 128
#define P_ 16384
#define C_ 64
#define NQ (B_*P_)   // 131072 rows

typedef _Float16 fp16;
typedef _Float16 half4v __attribute__((ext_vector_type(4)));

static __device__ __forceinline__ void fma4s(float4& a, float s, const float4& v) {
  a.x += s * v.x; a.y += s * v.y; a.z += s * v.z; a.w += s * v.w;
}
static __device__ __forceinline__ void fma4e(float4& a, const float4& u, const float4& v) {
  a.x += u.x * v.x; a.y += u.y * v.y; a.z += u.z * v.z; a.w += u.w * v.w;
}

// ---- K1: val GEMM, fp16 output. 128 rows/block, 8x4 tiles, 1024 blocks ----
__global__ __launch_bounds__(256) void gemm_val_kernel(
    const float* __restrict__ X, const float* __restrict__ W,
    const float* __restrict__ bias, fp16* __restrict__ val) {
  __shared__ __align__(16) float Xs[128][68];   // row-major, broadcast reads
  __shared__ __align__(16) float Ws[64][68];    // Ws[k][c] = W[c][k]
  int tid = threadIdx.x;
  int bid = blockIdx.x;
  int logical = (bid & 7) * 128 + (bid >> 3);   // batch<->XCD pinning
  size_t row0 = (size_t)logical * 128;

#pragma unroll
  for (int i0 = 0; i0 < 8192; i0 += 1024) {
    int i = i0 + tid * 4;
    int r = i >> 6, k = i & 63;
    *(float4*)&Xs[r][k] = *(const float4*)(X + row0 * 64 + i);
  }
#pragma unroll
  for (int i0 = 0; i0 < 4096; i0 += 1024) {
    int i = i0 + tid * 4;
    int c = i >> 6, k = i & 63;
    float4 wv = *(const float4*)(W + i);
    Ws[k][c] = wv.x; Ws[k + 1][c] = wv.y; Ws[k + 2][c] = wv.z; Ws[k + 3][c] = wv.w;
  }
  __syncthreads();

  int ty = tid >> 4, tx = tid & 15;
  int c0 = tx * 4;
  float4 b4 = *(const float4*)(bias + c0);
  float4 acc[8];
#pragma unroll
  for (int rr = 0; rr < 8; ++rr) acc[rr] = b4;
#pragma unroll 4
  for (int k0 = 0; k0 < 64; k0 += 4) {
    float4 w0 = *(const float4*)&Ws[k0][c0];
    float4 w1 = *(const float4*)&Ws[k0 + 1][c0];
    float4 w2 = *(const float4*)&Ws[k0 + 2][c0];
    float4 w3 = *(const float4*)&Ws[k0 + 3][c0];
#pragma unroll
    for (int rr = 0; rr < 8; ++rr) {
      float4 xv = *(const float4*)&Xs[ty + rr * 16][k0];   // 16-lane broadcast
      fma4s(acc[rr], xv.x, w0); fma4s(acc[rr], xv.y, w1);
      fma4s(acc[rr], xv.z, w2); fma4s(acc[rr], xv.w, w3);
    }
  }
#pragma unroll
  for (int rr = 0; rr < 8; ++rr) {
    int r = ty + rr * 16;
    half4v hv;
    hv.x = (fp16)acc[rr].x; hv.y = (fp16)acc[rr].y;
    hv.z = (fp16)acc[rr].z; hv.w = (fp16)acc[rr].w;
    *(half4v*)(val + (row0 + r) * 64 + c0) = hv;
  }
}

// ---- K2: depthwise 3x3 + offset/mask GEMM. 128 q/block (full image row) ----
__global__ __launch_bounds__(256) void dwom_kernel(
    const float* __restrict__ X, const float* __restrict__ dw_w,
    const float* __restrict__ dw_b, const float* __restrict__ om_w,
    const float* __restrict__ om_b, float* __restrict__ OM) {
  __shared__ __align__(16) float dws[128][68];   // row-major (68: c goes to 63 + pad)
  __shared__ __align__(16) float omwT[64][60];   // omwT[k][o] = om_w[o*64+k]
  __shared__ __align__(16) float dwwT[9][68];    // dwwT[t][c]
  __shared__ __align__(16) float dwbs[64];
  __shared__ __align__(16) float ombs[56];
  int tid = threadIdx.x;
  int bid = blockIdx.x;
  int logical = (bid & 7) * 128 + (bid >> 3);
  int q0 = logical * 128;
  int b = q0 >> 14;
  int h = logical & 127;

  for (int i = tid; i < 3456; i += 256) omwT[i & 63][i >> 6] = om_w[i];
  for (int i = tid; i < 576; i += 256) dwwT[i % 9][i / 9] = dw_w[i];
  if (tid < 64) dwbs[tid] = dw_b[tid];
  if (tid < 56) ombs[tid] = (tid < 54) ? om_b[tid] : 0.f;
  __syncthreads();

  // depthwise: 128 q x 64 c, float4 over c
  {
    int cv = tid & 15;
    int lqq = tid >> 4;
    int c0 = cv * 4;
    const float* xb = X + (size_t)b * 1048576;
    float4 wt[9];
#pragma unroll
    for (int t = 0; t < 9; ++t) wt[t] = *(const float4*)&dwwT[t][c0];
    float4 dwb4 = *(const float4*)&dwbs[c0];
#pragma unroll
    for (int it = 0; it < 8; ++it) {
      int lq = lqq + 16 * it;       // == w
      float4 acc = dwb4;
#pragma unroll
      for (int t = 0; t < 9; ++t) {
        int dy = t / 3 - 1, dx = t % 3 - 1;
        int hh = h + dy, wx = lq + dx;
        if ((unsigned)hh < 128u && (unsigned)wx < 128u) {
          float4 v = *(const float4*)(xb + (((size_t)(hh * 128 + wx)) << 6) + c0);
          fma4e(acc, v, wt[t]);
        }
      }
      *(float4*)&dws[lq][c0] = acc;
    }
  }
  __syncthreads();

  // GEMM: 128 q x 54 outs, 8x4 tiles
  int ty = tid >> 4, tx = tid & 15;
  int o0 = tx * 4;
  if (o0 < 54) {
    float4 b4 = *(const float4*)&ombs[o0];
    float4 acc[8];
#pragma unroll
    for (int rr = 0; rr < 8; ++rr) acc[rr] = b4;
#pragma unroll 4
    for (int k0 = 0; k0 < 64; k0 += 4) {
      float4 w0 = *(const float4*)&omwT[k0][o0];
      float4 w1 = *(const float4*)&omwT[k0 + 1][o0];
      float4 w2 = *(const float4*)&omwT[k0 + 2][o0];
      float4 w3 = *(const float4*)&omwT[k0 + 3][o0];
#pragma unroll
      for (int rr = 0; rr < 8; ++rr) {
        float4 dv = *(const float4*)&dws[ty + rr * 16][k0];
        fma4s(acc[rr], dv.x, w0); fma4s(acc[rr], dv.y, w1);
        fma4s(acc[rr], dv.z, w2); fma4s(acc[rr], dv.w, w3);
      }
    }
#pragma unroll
    for (int rr = 0; rr < 8; ++rr) {
      int r = ty + rr * 16;
      size_t base = (size_t)(q0 + r) * 54 + o0;
      if (o0 <= 48) {
        *(float4*)(OM + base) = acc[rr];
      } else {  // o0 == 52: last 2 valid
        *(float2*)(OM + base) = make_float2(acc[rr].x, acc[rr].y);
      }
    }
  }
}

// ---- K3: fused dcn gather (fp16 val) + output GEMM + halving + BN + ReLU ----
// 512 threads, 128 rows: p0..p0+63 (low) and p0+8192..+8255 (high pairs).
__global__ __launch_bounds__(512, 4) void dcn_fused_kernel(
    const fp16* __restrict__ val, const float* __restrict__ OM,
    const float* __restrict__ op_w, const float* __restrict__ op_b,
    const float* __restrict__ bn_g, const float* __restrict__ bn_b,
    const float* __restrict__ bn_m, const float* __restrict__ bn_v,
    float* __restrict__ out) {
  __shared__ __align__(16) float oms2[128 * 2 * 28];  // 28.7 KB [row][g][28]
  __shared__ __align__(16) float cs[128][68];         // 34.8 KB
  __shared__ __align__(16) float Ws[64][68];          // 17.4 KB
  int tid = threadIdx.x;
  int bid = blockIdx.x;
  int logical = (bid & 7) * 128 + (bid >> 3);
  int b = logical >> 7;                 // == bid & 7 (XCD pinned)
  int p0 = (logical & 127) << 6;
  int q0lo = b * 16384 + p0;

  // stage op_w transposed
#pragma unroll
  for (int i0 = 0; i0 < 4096; i0 += 2048) {
    int i = i0 + tid * 4;
    int c = i >> 6, k = i & 63;
    float4 wv = *(const float4*)(op_w + i);
    Ws[k][c] = wv.x; Ws[k + 1][c] = wv.y; Ws[k + 2][c] = wv.z; Ws[k + 3][c] = wv.w;
  }
  // stage OM into padded [row][g][28] layout (aligned float2 offset reads)
  {
    const float* srcLo = OM + (size_t)q0lo * 54;
    const float* srcHi = OM + (size_t)(q0lo + 8192) * 54;
    for (int j = tid; j < 6912; j += 512) {
      float v = (j < 3456) ? srcLo[j] : srcHi[j - 3456];
      int row = j / 54;
      int o = j - row * 54;
      int g = o >= 27;
      int oo = o - 27 * g;
      oms2[(row * 2 + g) * 28 + oo] = v;
    }
  }
  __syncthreads();

  // gather phase: 4 rows per thread
  {
    int lq = tid >> 4;
    int g = (tid >> 3) & 1;
    int dv = tid & 7;
    const fp16* vbase = val + ((size_t)b << 20) + g * 32 + dv * 4;
#pragma unroll
    for (int t = 0; t < 4; ++t) {
      int row = lq + 32 * t;
      int hi = row >> 6;
      int w = (p0 & 127) + (row & 63);
      int h = (p0 >> 7) + (hi << 6);
      const float* og = oms2 + (row * 2 + g) * 28;
      float fw = (float)w, fh = (float)h;
      float4 acc = make_float4(0.f, 0.f, 0.f, 0.f);
#pragma unroll
      for (int k = 0; k < 9; ++k) {
        float2 oxy = *(const float2*)(og + 2 * k);
        float m = og[18 + k];
        float ix = fw + ((float)(k % 3) - 1.0f + oxy.x) * 2.0f;
        float iy = fh + ((float)(k / 3) - 1.0f + oxy.y) * 2.0f;
        float x0f = floorf(ix), y0f = floorf(iy);
        float tx = ix - x0f, ty = iy - y0f;
        int x0 = (int)x0f, y0 = (int)y0f;
        int x1 = x0 + 1, y1 = y0 + 1;
        float vx0 = ((unsigned)x0 < 128u) ? 1.f : 0.f;
        float vx1 = ((unsigned)x1 < 128u) ? 1.f : 0.f;
        float vy0 = ((unsigned)y0 < 128u) ? 1.f : 0.f;
        float vy1 = ((unsigned)y1 < 128u) ? 1.f : 0.f;
        int xc0 = min(max(x0, 0), 127), xc1 = min(max(x1, 0), 127);
        int yc0 = min(max(y0, 0), 127), yc1 = min(max(y1, 0), 127);
        float w00 = (1.f - ty) * (1.f - tx) * m * vy0 * vx0;
        float w01 = (1.f - ty) * tx * m * vy0 * vx1;
        float w10 = ty * (1.f - tx) * m * vy1 * vx0;
        float w11 = ty * tx * m * vy1 * vx1;
        half4v v00 = *(const half4v*)(vbase + ((size_t)((yc0 * 128 + xc0)) << 6));
        half4v v01 = *(const half4v*)(vbase + ((size_t)((yc0 * 128 + xc1)) << 6));
        half4v v10 = *(const half4v*)(vbase + ((size_t)((yc1 * 128 + xc0)) << 6));
        half4v v11 = *(const half4v*)(vbase + ((size_t)((yc1 * 128 + xc1)) << 6));
        float4 f00 = {(float)v00.x, (float)v00.y, (float)v00.z, (float)v00.w};
        float4 f01 = {(float)v01.x, (float)v01.y, (float)v01.z, (float)v01.w};
        float4 f10 = {(float)v10.x, (float)v10.y, (float)v10.z, (float)v10.w};
        float4 f11 = {(float)v11.x, (float)v11.y, (float)v11.z, (float)v11.w};
        fma4s(acc, w00, f00); fma4s(acc, w01, f01);
        fma4s(acc, w10, f10); fma4s(acc, w11, f11);
      }
      *(float4*)&cs[row][g * 32 + dv * 4] = acc;
    }
  }
  __syncthreads();

  // GEMM + halving + BN + ReLU: threads 0..255 active, 4 out-rows x 4 cols each
  int tyg = tid >> 4;
  int txg = tid & 15;
  if (tyg < 16) {
    int c0 = txg * 4;
    float4 accL[4], accH[4];
#pragma unroll
    for (int m = 0; m < 4; ++m) {
      accL[m] = make_float4(0.f, 0.f, 0.f, 0.f);
      accH[m] = make_float4(0.f, 0.f, 0.f, 0.f);
    }
#pragma unroll 2
    for (int k0 = 0; k0 < 64; k0 += 4) {
      float4 w0 = *(const float4*)&Ws[k0][c0];
      float4 w1 = *(const float4*)&Ws[k0 + 1][c0];
      float4 w2 = *(const float4*)&Ws[k0 + 2][c0];
      float4 w3 = *(const float4*)&Ws[k0 + 3][c0];
#pragma unroll
      for (int m = 0; m < 4; ++m) {
        int r = tyg + 16 * m;
        float4 aL = *(const float4*)&cs[r][k0];
        float4 aH = *(const float4*)&cs[r + 64][k0];
        fma4s(accL[m], aL.x, w0); fma4s(accL[m], aL.y, w1);
        fma4s(accL[m], aL.z, w2); fma4s(accL[m], aL.w, w3);
        fma4s(accH[m], aH.x, w0); fma4s(accH[m], aH.y, w1);
        fma4s(accH[m], aH.z, w2); fma4s(accH[m], aH.w, w3);
      }
    }
    float4 bias4 = *(const float4*)(op_b + c0);
#pragma unroll
    for (int m = 0; m < 4; ++m) {
      int r = tyg + 16 * m;
      int f = (p0 + r) * 64 + c0;        // within-batch flat position
      int c2 = f >> 14;
      float scale = bn_g[c2] * rsqrtf(bn_v[c2] + 1e-5f);
      float shift = bn_b[c2] - bn_m[c2] * scale;
      float4 z;
      z.x = fmaxf((0.5f * (accL[m].x + accH[m].x) + bias4.x) * scale + shift, 0.f);
      z.y = fmaxf((0.5f * (accL[m].y + accH[m].y) + bias4.y) * scale + shift, 0.f);
      z.z = fmaxf((0.5f * (accL[m].z + accH[m].z) + bias4.z) * scale + shift, 0.f);
      z.w = fmaxf((0.5f * (accL[m].w + accH[m].w) + bias4.w) * scale + shift, 0.f);
      *(float4*)(out + (size_t)b * 524288 + f) = z;
    }
  }
}

extern "C" void kernel_launch(void* const* d_in, const int* in_sizes, int n_in,
                              void* d_out, int out_size, void* d_ws, size_t ws_size,
                              hipStream_t stream) {
  const float* x    = (const float*)d_in[0];
  const float* vp_w = (const float*)d_in[1];
  const float* vp_b = (const float*)d_in[2];
  const float* dw_w = (const float*)d_in[3];
  const float* dw_b = (const float*)d_in[4];
  const float* om_w = (const float*)d_in[5];
  const float* om_b = (const float*)d_in[6];
  const float* op_w = (const float*)d_in[7];
  const float* op_b = (const float*)d_in[8];
  const float* bn_g = (const float*)d_in[9];
  const float* bn_b = (const float*)d_in[10];
  const float* bn_m = (const float*)d_in[11];
  const float* bn_v = (const float*)d_in[12];

  float* ws   = (float*)d_ws;
  fp16* val_h = (fp16*)d_ws;         // 131072*64 fp16 = 16 MB
  float* om   = ws + 16777216;       // byte offset 64 MB; 27 MB

  gemm_val_kernel<<<dim3(1024), dim3(256), 0, stream>>>(x, vp_w, vp_b, val_h);
  dwom_kernel<<<dim3(1024), dim3(256), 0, stream>>>(x, dw_w, dw_b, om_w, om_b, om);
  dcn_fused_kernel<<<dim3(1024), dim3(512), 0, stream>>>(
      val_h, om, op_w, op_b, bn_g, bn_b, bn_m, bn_v, (float*)d_out);
}

// Round 7
// 126.958 us; speedup vs baseline: 1.0713x; 1.0713x over previous
//
#include <hip/hip_runtime.h>

#define B_ 8
#define H_ 128
#define W_ 128
#define P_ 16384
#define C_ 64
#define NQ (B_*P_)   // 131072 rows

typedef _Float16 fp16;
typedef _Float16 half2v __attribute__((ext_vector_type(2)));
typedef _Float16 half4v __attribute__((ext_vector_type(4)));
typedef _Float16 half8v __attribute__((ext_vector_type(8)));

static __device__ __forceinline__ void fma4s(float4& a, float s, const float4& v) {
  a.x += s * v.x; a.y += s * v.y; a.z += s * v.z; a.w += s * v.w;
}
static __device__ __forceinline__ void fma4e(float4& a, const float4& u, const float4& v) {
  a.x += u.x * v.x; a.y += u.y * v.y; a.z += u.z * v.z; a.w += u.w * v.w;
}
static __device__ __forceinline__ float4 h2f(half4v h) {
  return make_float4((float)h.x, (float)h.y, (float)h.z, (float)h.w);
}

// ---- K1: val GEMM, fp16 output. 128 rows/block, 8x4 tiles, 1024 blocks ----
__global__ __launch_bounds__(256) void gemm_val_kernel(
    const float* __restrict__ X, const float* __restrict__ W,
    const float* __restrict__ bias, fp16* __restrict__ val) {
  __shared__ __align__(16) float Xs[128][68];
  __shared__ __align__(16) float Ws[64][68];
  int tid = threadIdx.x;
  int bid = blockIdx.x;
  int logical = (bid & 7) * 128 + (bid >> 3);   // batch<->XCD pinning
  size_t row0 = (size_t)logical * 128;

#pragma unroll
  for (int i0 = 0; i0 < 8192; i0 += 1024) {
    int i = i0 + tid * 4;
    int r = i >> 6, k = i & 63;
    *(float4*)&Xs[r][k] = *(const float4*)(X + row0 * 64 + i);
  }
#pragma unroll
  for (int i0 = 0; i0 < 4096; i0 += 1024) {
    int i = i0 + tid * 4;
    int c = i >> 6, k = i & 63;
    float4 wv = *(const float4*)(W + i);
    Ws[k][c] = wv.x; Ws[k + 1][c] = wv.y; Ws[k + 2][c] = wv.z; Ws[k + 3][c] = wv.w;
  }
  __syncthreads();

  int ty = tid >> 4, tx = tid & 15;
  int c0 = tx * 4;
  float4 b4 = *(const float4*)(bias + c0);
  float4 acc[8];
#pragma unroll
  for (int rr = 0; rr < 8; ++rr) acc[rr] = b4;
#pragma unroll 4
  for (int k0 = 0; k0 < 64; k0 += 4) {
    float4 w0 = *(const float4*)&Ws[k0][c0];
    float4 w1 = *(const float4*)&Ws[k0 + 1][c0];
    float4 w2 = *(const float4*)&Ws[k0 + 2][c0];
    float4 w3 = *(const float4*)&Ws[k0 + 3][c0];
#pragma unroll
    for (int rr = 0; rr < 8; ++rr) {
      float4 xv = *(const float4*)&Xs[ty + rr * 16][k0];
      fma4s(acc[rr], xv.x, w0); fma4s(acc[rr], xv.y, w1);
      fma4s(acc[rr], xv.z, w2); fma4s(acc[rr], xv.w, w3);
    }
  }
#pragma unroll
  for (int rr = 0; rr < 8; ++rr) {
    int r = ty + rr * 16;
    half4v hv;
    hv.x = (fp16)acc[rr].x; hv.y = (fp16)acc[rr].y;
    hv.z = (fp16)acc[rr].z; hv.w = (fp16)acc[rr].w;
    *(half4v*)(val + (row0 + r) * 64 + c0) = hv;
  }
}

// ---- K2: depthwise 3x3 + offset/mask GEMM -> fp16 OM. 128 q/block ----
__global__ __launch_bounds__(256) void dwom_kernel(
    const float* __restrict__ X, const float* __restrict__ dw_w,
    const float* __restrict__ dw_b, const float* __restrict__ om_w,
    const float* __restrict__ om_b, fp16* __restrict__ OM) {
  __shared__ __align__(16) float dws[128][68];
  __shared__ __align__(16) float omwT[64][60];
  __shared__ __align__(16) float dwwT[9][68];
  __shared__ __align__(16) float dwbs[64];
  __shared__ __align__(16) float ombs[56];
  int tid = threadIdx.x;
  int bid = blockIdx.x;
  int logical = (bid & 7) * 128 + (bid >> 3);
  int q0 = logical * 128;
  int b = q0 >> 14;
  int h = logical & 127;

  for (int i = tid; i < 3456; i += 256) omwT[i & 63][i >> 6] = om_w[i];
  for (int i = tid; i < 576; i += 256) dwwT[i % 9][i / 9] = dw_w[i];
  if (tid < 64) dwbs[tid] = dw_b[tid];
  if (tid < 56) ombs[tid] = (tid < 54) ? om_b[tid] : 0.f;
  __syncthreads();

  {
    int cv = tid & 15;
    int lqq = tid >> 4;
    int c0 = cv * 4;
    const float* xb = X + (size_t)b * 1048576;
    float4 wt[9];
#pragma unroll
    for (int t = 0; t < 9; ++t) wt[t] = *(const float4*)&dwwT[t][c0];
    float4 dwb4 = *(const float4*)&dwbs[c0];
#pragma unroll
    for (int it = 0; it < 8; ++it) {
      int lq = lqq + 16 * it;       // == w
      float4 acc = dwb4;
#pragma unroll
      for (int t = 0; t < 9; ++t) {
        int dy = t / 3 - 1, dx = t % 3 - 1;
        int hh = h + dy, wx = lq + dx;
        if ((unsigned)hh < 128u && (unsigned)wx < 128u) {
          float4 v = *(const float4*)(xb + (((size_t)(hh * 128 + wx)) << 6) + c0);
          fma4e(acc, v, wt[t]);
        }
      }
      *(float4*)&dws[lq][c0] = acc;
    }
  }
  __syncthreads();

  int ty = tid >> 4, tx = tid & 15;
  int o0 = tx * 4;
  if (o0 < 54) {
    float4 b4 = *(const float4*)&ombs[o0];
    float4 acc[8];
#pragma unroll
    for (int rr = 0; rr < 8; ++rr) acc[rr] = b4;
#pragma unroll 4
    for (int k0 = 0; k0 < 64; k0 += 4) {
      float4 w0 = *(const float4*)&omwT[k0][o0];
      float4 w1 = *(const float4*)&omwT[k0 + 1][o0];
      float4 w2 = *(const float4*)&omwT[k0 + 2][o0];
      float4 w3 = *(const float4*)&omwT[k0 + 3][o0];
#pragma unroll
      for (int rr = 0; rr < 8; ++rr) {
        float4 dv = *(const float4*)&dws[ty + rr * 16][k0];
        fma4s(acc[rr], dv.x, w0); fma4s(acc[rr], dv.y, w1);
        fma4s(acc[rr], dv.z, w2); fma4s(acc[rr], dv.w, w3);
      }
    }
#pragma unroll
    for (int rr = 0; rr < 8; ++rr) {
      int r = ty + rr * 16;
      size_t base = (size_t)(q0 + r) * 54 + o0;
      if (o0 <= 48) {
        half4v hv;
        hv.x = (fp16)acc[rr].x; hv.y = (fp16)acc[rr].y;
        hv.z = (fp16)acc[rr].z; hv.w = (fp16)acc[rr].w;
        *(half4v*)(OM + base) = hv;            // 4B-aligned (q*54+o0)*2
      } else {  // o0 == 52: last 2 valid
        half2v hv2;
        hv2.x = (fp16)acc[rr].x; hv2.y = (fp16)acc[rr].y;
        *(half2v*)(OM + base) = hv2;
      }
    }
  }
}

// ---- K3a: dcn gather, weights precomputed in LDS, fp16 in/out ----
// 64 q rows/block, 2048 blocks, 23KB LDS.
__global__ __launch_bounds__(256, 6) void gather_kernel(
    const fp16* __restrict__ val, const fp16* __restrict__ OM,
    fp16* __restrict__ core) {
  __shared__ __align__(16) float4 wtab[64 * 2 * 9];  // 18.4 KB
  __shared__ int btab[64 * 2 * 9];                   // 4.6 KB
  int tid = threadIdx.x;
  int bid = blockIdx.x;
  int logical = (bid & 7) * 256 + (bid >> 3);   // XCD pinning: bid&7 == batch
  int b = logical >> 8;
  int q0 = logical * 64;

  // precompute bilinear weights + packed corner base per (row, g, k)
  for (int i = tid; i < 1152; i += 256) {
    int row = i / 18;
    int rem = i - row * 18;
    int g = rem / 9;
    int k = rem - g * 9;
    int q = q0 + row;
    int p = q & 16383;
    int h = p >> 7, w = p & 127;
    const fp16* omq = OM + (size_t)q * 54 + g * 27;
    float ox = (float)omq[2 * k], oy = (float)omq[2 * k + 1];
    float m = (float)omq[18 + k];
    int kx = k - (k / 3) * 3, ky = k / 3;
    float ix = (float)w + ((float)kx - 1.0f + ox) * 2.0f;
    float iy = (float)h + ((float)ky - 1.0f + oy) * 2.0f;
    float x0f = floorf(ix), y0f = floorf(iy);
    float tx = ix - x0f, ty = iy - y0f;
    int x0 = (int)x0f, y0 = (int)y0f;
    int x1 = x0 + 1, y1 = y0 + 1;
    float vx0 = ((unsigned)x0 < 128u) ? 1.f : 0.f;
    float vx1 = ((unsigned)x1 < 128u) ? 1.f : 0.f;
    float vy0 = ((unsigned)y0 < 128u) ? 1.f : 0.f;
    float vy1 = ((unsigned)y1 < 128u) ? 1.f : 0.f;
    int xc0 = min(max(x0, 0), 127), xc1 = min(max(x1, 0), 127);
    int yc0 = min(max(y0, 0), 127), yc1 = min(max(y1, 0), 127);
    float4 w4;
    w4.x = (1.f - ty) * (1.f - tx) * m * vy0 * vx0;
    w4.y = (1.f - ty) * tx * m * vy0 * vx1;
    w4.z = ty * (1.f - tx) * m * vy1 * vx0;
    w4.w = ty * tx * m * vy1 * vx1;
    wtab[i] = w4;
    btab[i] = (yc0 * 128 + xc0) | ((xc1 - xc0) << 14) | ((yc1 - yc0) << 15);
  }
  __syncthreads();

  int lq = tid >> 4;        // 0..15
  int g = (tid >> 3) & 1;
  int dv = tid & 7;
  const fp16* vbase = val + ((size_t)b << 20) + g * 32 + dv * 4;
  fp16* cbase = core + (size_t)q0 * 64 + g * 32 + dv * 4;
  for (int t = 0; t < 4; ++t) {
    int row = lq + 16 * t;
    int base = (row * 2 + g) * 9;
    float4 acc = make_float4(0.f, 0.f, 0.f, 0.f);
#pragma unroll
    for (int k = 0; k < 9; ++k) {
      float4 w4 = wtab[base + k];
      int pk = btab[base + k];
      int lin00 = pk & 16383;
      int dxo = (pk >> 14) & 1;
      int lin10 = lin00 + ((pk >> 15) << 7);
      half4v v00 = *(const half4v*)(vbase + ((size_t)lin00 << 6));
      half4v v01 = *(const half4v*)(vbase + ((size_t)(lin00 + dxo) << 6));
      half4v v10 = *(const half4v*)(vbase + ((size_t)lin10 << 6));
      half4v v11 = *(const half4v*)(vbase + ((size_t)(lin10 + dxo) << 6));
      fma4s(acc, w4.x, h2f(v00));
      fma4s(acc, w4.y, h2f(v01));
      fma4s(acc, w4.z, h2f(v10));
      fma4s(acc, w4.w, h2f(v11));
    }
    half4v hv;
    hv.x = (fp16)acc.x; hv.y = (fp16)acc.y; hv.z = (fp16)acc.z; hv.w = (fp16)acc.w;
    *(half4v*)(cbase + ((size_t)row << 6)) = hv;
  }
}

// ---- K3b: output GEMM + halves-avg + BN + ReLU. 64 out-rows/block ----
__global__ __launch_bounds__(256) void gemmbn_kernel(
    const fp16* __restrict__ core, const float* __restrict__ op_w,
    const float* __restrict__ op_b, const float* __restrict__ bn_g,
    const float* __restrict__ bn_b, const float* __restrict__ bn_m,
    const float* __restrict__ bn_v, float* __restrict__ out) {
  __shared__ __align__(16) float Ws[64][68];     // 17.4 KB
  __shared__ __align__(16) fp16 csL[64][72];     // 9.2 KB
  __shared__ __align__(16) fp16 csH[64][72];     // 9.2 KB
  int tid = threadIdx.x;
  int bid = blockIdx.x;
  int logical = (bid & 7) * 128 + (bid >> 3);    // XCD pinning
  int b = logical >> 7;
  int p0 = (logical & 127) * 64;                 // 0..8128
  size_t q0lo = (size_t)b * 16384 + p0;

#pragma unroll
  for (int i0 = 0; i0 < 4096; i0 += 1024) {
    int i = i0 + tid * 4;
    int c = i >> 6, k = i & 63;
    float4 wv = *(const float4*)(op_w + i);
    Ws[k][c] = wv.x; Ws[k + 1][c] = wv.y; Ws[k + 2][c] = wv.z; Ws[k + 3][c] = wv.w;
  }
  // stage 64 low + 64 high core rows (fp16), 16B per load
#pragma unroll
  for (int j0 = 0; j0 < 512; j0 += 256) {
    int j = j0 + tid;
    int r = j >> 3;
    int cc = (j & 7) * 8;
    *(half8v*)&csL[r][cc] = *(const half8v*)(core + (q0lo + r) * 64 + cc);
    *(half8v*)&csH[r][cc] = *(const half8v*)(core + (q0lo + 8192 + r) * 64 + cc);
  }
  __syncthreads();

  int ty = tid >> 4, tx = tid & 15;
  int c0 = tx * 4;
  float4 accL[4], accH[4];
#pragma unroll
  for (int m = 0; m < 4; ++m) {
    accL[m] = make_float4(0.f, 0.f, 0.f, 0.f);
    accH[m] = make_float4(0.f, 0.f, 0.f, 0.f);
  }
#pragma unroll 2
  for (int k0 = 0; k0 < 64; k0 += 4) {
    float4 w0 = *(const float4*)&Ws[k0][c0];
    float4 w1 = *(const float4*)&Ws[k0 + 1][c0];
    float4 w2 = *(const float4*)&Ws[k0 + 2][c0];
    float4 w3 = *(const float4*)&Ws[k0 + 3][c0];
#pragma unroll
    for (int m = 0; m < 4; ++m) {
      int r = ty + 16 * m;
      float4 aL = h2f(*(const half4v*)&csL[r][k0]);
      float4 aH = h2f(*(const half4v*)&csH[r][k0]);
      fma4s(accL[m], aL.x, w0); fma4s(accL[m], aL.y, w1);
      fma4s(accL[m], aL.z, w2); fma4s(accL[m], aL.w, w3);
      fma4s(accH[m], aH.x, w0); fma4s(accH[m], aH.y, w1);
      fma4s(accH[m], aH.z, w2); fma4s(accH[m], aH.w, w3);
    }
  }
  float4 bias4 = *(const float4*)(op_b + c0);
#pragma unroll
  for (int m = 0; m < 4; ++m) {
    int r = ty + 16 * m;
    int f = (p0 + r) * 64 + c0;          // within-batch z-flat position
    int c2 = f >> 14;
    float scale = bn_g[c2] * rsqrtf(bn_v[c2] + 1e-5f);
    float shift = bn_b[c2] - bn_m[c2] * scale;
    float4 z;
    z.x = fmaxf((0.5f * (accL[m].x + accH[m].x) + bias4.x) * scale + shift, 0.f);
    z.y = fmaxf((0.5f * (accL[m].y + accH[m].y) + bias4.y) * scale + shift, 0.f);
    z.z = fmaxf((0.5f * (accL[m].z + accH[m].z) + bias4.z) * scale + shift, 0.f);
    z.w = fmaxf((0.5f * (accL[m].w + accH[m].w) + bias4.w) * scale + shift, 0.f);
    *(float4*)(out + (size_t)b * 524288 + f) = z;
  }
}

extern "C" void kernel_launch(void* const* d_in, const int* in_sizes, int n_in,
                              void* d_out, int out_size, void* d_ws, size_t ws_size,
                              hipStream_t stream) {
  const float* x    = (const float*)d_in[0];
  const float* vp_w = (const float*)d_in[1];
  const float* vp_b = (const float*)d_in[2];
  const float* dw_w = (const float*)d_in[3];
  const float* dw_b = (const float*)d_in[4];
  const float* om_w = (const float*)d_in[5];
  const float* om_b = (const float*)d_in[6];
  const float* op_w = (const float*)d_in[7];
  const float* op_b = (const float*)d_in[8];
  const float* bn_g = (const float*)d_in[9];
  const float* bn_b = (const float*)d_in[10];
  const float* bn_m = (const float*)d_in[11];
  const float* bn_v = (const float*)d_in[12];

  fp16* val_h  = (fp16*)d_ws;                           // 16 MB
  fp16* core_h = (fp16*)((char*)d_ws + (16u << 20));    // 16 MB
  fp16* om_h   = (fp16*)((char*)d_ws + (32u << 20));    // 13.5 MB

  gemm_val_kernel<<<dim3(1024), dim3(256), 0, stream>>>(x, vp_w, vp_b, val_h);
  dwom_kernel<<<dim3(1024), dim3(256), 0, stream>>>(x, dw_w, dw_b, om_w, om_b, om_h);
  gather_kernel<<<dim3(2048), dim3(256), 0, stream>>>(val_h, om_h, core_h);
  gemmbn_kernel<<<dim3(1024), dim3(256), 0, stream>>>(
      core_h, op_w, op_b, bn_g, bn_b, bn_m, bn_v, (float*)d_out);
}

// Round 8
// 120.539 us; speedup vs baseline: 1.1283x; 1.0533x over previous
//
#include <hip/hip_runtime.h>

#define B_ 8
#define H_ 128
#define W_ 128
#define P_ 16384
#define C_ 64
#define NQ (B_*P_)   // 131072 rows

typedef _Float16 fp16;
typedef _Float16 half2v __attribute__((ext_vector_type(2)));
typedef _Float16 half4v __attribute__((ext_vector_type(4)));
typedef _Float16 half8v __attribute__((ext_vector_type(8)));

static __device__ __forceinline__ void fma4s(float4& a, float s, const float4& v) {
  a.x += s * v.x; a.y += s * v.y; a.z += s * v.z; a.w += s * v.w;
}
static __device__ __forceinline__ void fma4e(float4& a, const float4& u, const float4& v) {
  a.x += u.x * v.x; a.y += u.y * v.y; a.z += u.z * v.z; a.w += u.w * v.w;
}
static __device__ __forceinline__ float4 h2f(half4v h) {
  return make_float4((float)h.x, (float)h.y, (float)h.z, (float)h.w);
}
static __device__ __forceinline__ half4v f2h(float4 a) {
  half4v hv;
  hv.x = (fp16)a.x; hv.y = (fp16)a.y; hv.z = (fp16)a.z; hv.w = (fp16)a.w;
  return hv;
}

// ---- K1: val GEMM, fp16 output. 128 rows/block, 8x4 tiles, 1024 blocks ----
__global__ __launch_bounds__(256) void gemm_val_kernel(
    const float* __restrict__ X, const float* __restrict__ W,
    const float* __restrict__ bias, fp16* __restrict__ val) {
  __shared__ __align__(16) float Xs[128][68];
  __shared__ __align__(16) float Ws[64][68];
  int tid = threadIdx.x;
  int bid = blockIdx.x;
  int logical = (bid & 7) * 128 + (bid >> 3);   // batch<->XCD pinning
  size_t row0 = (size_t)logical * 128;

#pragma unroll
  for (int i0 = 0; i0 < 8192; i0 += 1024) {
    int i = i0 + tid * 4;
    int r = i >> 6, k = i & 63;
    *(float4*)&Xs[r][k] = *(const float4*)(X + row0 * 64 + i);
  }
#pragma unroll
  for (int i0 = 0; i0 < 4096; i0 += 1024) {
    int i = i0 + tid * 4;
    int c = i >> 6, k = i & 63;
    float4 wv = *(const float4*)(W + i);
    Ws[k][c] = wv.x; Ws[k + 1][c] = wv.y; Ws[k + 2][c] = wv.z; Ws[k + 3][c] = wv.w;
  }
  __syncthreads();

  int ty = tid >> 4, tx = tid & 15;
  int c0 = tx * 4;
  float4 b4 = *(const float4*)(bias + c0);
  float4 acc[8];
#pragma unroll
  for (int rr = 0; rr < 8; ++rr) acc[rr] = b4;
#pragma unroll 4
  for (int k0 = 0; k0 < 64; k0 += 4) {
    float4 w0 = *(const float4*)&Ws[k0][c0];
    float4 w1 = *(const float4*)&Ws[k0 + 1][c0];
    float4 w2 = *(const float4*)&Ws[k0 + 2][c0];
    float4 w3 = *(const float4*)&Ws[k0 + 3][c0];
#pragma unroll
    for (int rr = 0; rr < 8; ++rr) {
      float4 xv = *(const float4*)&Xs[ty + rr * 16][k0];
      fma4s(acc[rr], xv.x, w0); fma4s(acc[rr], xv.y, w1);
      fma4s(acc[rr], xv.z, w2); fma4s(acc[rr], xv.w, w3);
    }
  }
#pragma unroll
  for (int rr = 0; rr < 8; ++rr) {
    int r = ty + rr * 16;
    *(half4v*)(val + (row0 + r) * 64 + c0) = f2h(acc[rr]);
  }
}

// ---- K2: depthwise 3x3 (sliding window) + offset/mask GEMM -> fp16 OM ----
// 128 q/block (one image row), 1024 blocks, ~36.7 KB LDS -> 4 blocks/CU.
__global__ __launch_bounds__(256) void dwom_kernel(
    const float* __restrict__ X, const float* __restrict__ dw_w,
    const float* __restrict__ dw_b, const float* __restrict__ om_w,
    const float* __restrict__ om_b, fp16* __restrict__ OM) {
  __shared__ __align__(16) fp16 dws[128][72];    // 18.4 KB, row-major [w][c]
  __shared__ __align__(16) float omwT[64][60];   // 15.4 KB, omwT[k][o]
  __shared__ __align__(16) float dwwT[9][68];    // 2.4 KB, dwwT[t][c]
  __shared__ float dwbs[64];
  __shared__ float ombs[56];
  int tid = threadIdx.x;
  int bid = blockIdx.x;
  int logical = (bid & 7) * 128 + (bid >> 3);    // XCD pinning
  int q0 = logical * 128;
  int b = q0 >> 14;
  int h = logical & 127;

  for (int i = tid; i < 3456; i += 256) omwT[i & 63][i >> 6] = om_w[i];
  for (int i = tid; i < 576; i += 256) dwwT[i % 9][i / 9] = dw_w[i];
  if (tid < 64) dwbs[tid] = dw_b[tid];
  if (tid < 56) ombs[tid] = (tid < 54) ? om_b[tid] : 0.f;
  __syncthreads();

  // ---- depthwise: thread = (c-chunk, 8 consecutive w), rolling 3x3 window ----
  {
    int cv = tid & 15;
    int wq = tid >> 4;
    int c0 = cv * 4;
    int wbase = wq * 8;
    const float* xb = X + (size_t)b * 1048576 + c0;
    const float* rp0 = xb + (size_t)(h - 1) * 8192;
    const float* rp1 = xb + (size_t)h * 8192;
    const float* rp2 = xb + (size_t)(h + 1) * 8192;
    bool v0 = (h > 0), v2 = (h < 127);
    float4 wt[9];
#pragma unroll
    for (int t = 0; t < 9; ++t) wt[t] = *(const float4*)&dwwT[t][c0];
    float4 dwb4 = *(const float4*)&dwbs[c0];
    const float4 z4 = make_float4(0.f, 0.f, 0.f, 0.f);
    bool vm = (wbase > 0);
    float4 cm0 = (vm && v0) ? *(const float4*)(rp0 + (wbase - 1) * 64) : z4;
    float4 cm1 = vm         ? *(const float4*)(rp1 + (wbase - 1) * 64) : z4;
    float4 cm2 = (vm && v2) ? *(const float4*)(rp2 + (wbase - 1) * 64) : z4;
    float4 cc0 = v0 ? *(const float4*)(rp0 + wbase * 64) : z4;
    float4 cc1 =      *(const float4*)(rp1 + wbase * 64);
    float4 cc2 = v2 ? *(const float4*)(rp2 + wbase * 64) : z4;
#pragma unroll
    for (int j = 0; j < 8; ++j) {
      int w = wbase + j;
      bool vn = (w < 127);
      float4 cn0 = (vn && v0) ? *(const float4*)(rp0 + (w + 1) * 64) : z4;
      float4 cn1 = vn         ? *(const float4*)(rp1 + (w + 1) * 64) : z4;
      float4 cn2 = (vn && v2) ? *(const float4*)(rp2 + (w + 1) * 64) : z4;
      float4 acc = dwb4;
      fma4e(acc, cm0, wt[0]); fma4e(acc, cc0, wt[1]); fma4e(acc, cn0, wt[2]);
      fma4e(acc, cm1, wt[3]); fma4e(acc, cc1, wt[4]); fma4e(acc, cn1, wt[5]);
      fma4e(acc, cm2, wt[6]); fma4e(acc, cc2, wt[7]); fma4e(acc, cn2, wt[8]);
      *(half4v*)&dws[w][c0] = f2h(acc);
      cm0 = cc0; cm1 = cc1; cm2 = cc2;
      cc0 = cn0; cc1 = cn1; cc2 = cn2;
    }
  }
  __syncthreads();

  // ---- GEMM: 128 q x 54 outs, 8x4 tiles ----
  int ty = tid >> 4, tx = tid & 15;
  int o0 = tx * 4;
  if (o0 < 54) {
    float4 b4 = *(const float4*)&ombs[o0];
    float4 acc[8];
#pragma unroll
    for (int rr = 0; rr < 8; ++rr) acc[rr] = b4;
#pragma unroll 4
    for (int k0 = 0; k0 < 64; k0 += 4) {
      float4 w0 = *(const float4*)&omwT[k0][o0];
      float4 w1 = *(const float4*)&omwT[k0 + 1][o0];
      float4 w2 = *(const float4*)&omwT[k0 + 2][o0];
      float4 w3 = *(const float4*)&omwT[k0 + 3][o0];
#pragma unroll
      for (int rr = 0; rr < 8; ++rr) {
        float4 dv = h2f(*(const half4v*)&dws[ty + rr * 16][k0]);
        fma4s(acc[rr], dv.x, w0); fma4s(acc[rr], dv.y, w1);
        fma4s(acc[rr], dv.z, w2); fma4s(acc[rr], dv.w, w3);
      }
    }
#pragma unroll
    for (int rr = 0; rr < 8; ++rr) {
      int r = ty + rr * 16;
      size_t base = (size_t)(q0 + r) * 54 + o0;
      if (o0 <= 48) {
        *(half4v*)(OM + base) = f2h(acc[rr]);
      } else {  // o0 == 52: last 2 valid
        half2v hv2;
        hv2.x = (fp16)acc[rr].x; hv2.y = (fp16)acc[rr].y;
        *(half2v*)(OM + base) = hv2;
      }
    }
  }
}

// ---- K3a: dcn gather, weights precomputed in LDS, fp16 in/out ----
// 64 q rows/block, 2048 blocks, 23KB LDS.
__global__ __launch_bounds__(256, 6) void gather_kernel(
    const fp16* __restrict__ val, const fp16* __restrict__ OM,
    fp16* __restrict__ core) {
  __shared__ __align__(16) float4 wtab[64 * 2 * 9];  // 18.4 KB
  __shared__ int btab[64 * 2 * 9];                   // 4.6 KB
  int tid = threadIdx.x;
  int bid = blockIdx.x;
  int logical = (bid & 7) * 256 + (bid >> 3);   // XCD pinning: bid&7 == batch
  int b = logical >> 8;
  int q0 = logical * 64;

  // precompute bilinear weights + packed corner base per (row, g, k)
  for (int i = tid; i < 1152; i += 256) {
    int row = i / 18;
    int rem = i - row * 18;
    int g = rem / 9;
    int k = rem - g * 9;
    int q = q0 + row;
    int p = q & 16383;
    int h = p >> 7, w = p & 127;
    const fp16* omq = OM + (size_t)q * 54 + g * 27;
    float ox = (float)omq[2 * k], oy = (float)omq[2 * k + 1];
    float m = (float)omq[18 + k];
    int kx = k - (k / 3) * 3, ky = k / 3;
    float ix = (float)w + ((float)kx - 1.0f + ox) * 2.0f;
    float iy = (float)h + ((float)ky - 1.0f + oy) * 2.0f;
    float x0f = floorf(ix), y0f = floorf(iy);
    float tx = ix - x0f, ty = iy - y0f;
    int x0 = (int)x0f, y0 = (int)y0f;
    int x1 = x0 + 1, y1 = y0 + 1;
    float vx0 = ((unsigned)x0 < 128u) ? 1.f : 0.f;
    float vx1 = ((unsigned)x1 < 128u) ? 1.f : 0.f;
    float vy0 = ((unsigned)y0 < 128u) ? 1.f : 0.f;
    float vy1 = ((unsigned)y1 < 128u) ? 1.f : 0.f;
    int xc0 = min(max(x0, 0), 127), xc1 = min(max(x1, 0), 127);
    int yc0 = min(max(y0, 0), 127), yc1 = min(max(y1, 0), 127);
    float4 w4;
    w4.x = (1.f - ty) * (1.f - tx) * m * vy0 * vx0;
    w4.y = (1.f - ty) * tx * m * vy0 * vx1;
    w4.z = ty * (1.f - tx) * m * vy1 * vx0;
    w4.w = ty * tx * m * vy1 * vx1;
    wtab[i] = w4;
    btab[i] = (yc0 * 128 + xc0) | ((xc1 - xc0) << 14) | ((yc1 - yc0) << 15);
  }
  __syncthreads();

  int lq = tid >> 4;        // 0..15
  int g = (tid >> 3) & 1;
  int dv = tid & 7;
  const fp16* vbase = val + ((size_t)b << 20) + g * 32 + dv * 4;
  fp16* cbase = core + (size_t)q0 * 64 + g * 32 + dv * 4;
  for (int t = 0; t < 4; ++t) {
    int row = lq + 16 * t;
    int base = (row * 2 + g) * 9;
    float4 acc = make_float4(0.f, 0.f, 0.f, 0.f);
#pragma unroll
    for (int k = 0; k < 9; ++k) {
      float4 w4 = wtab[base + k];
      int pk = btab[base + k];
      int lin00 = pk & 16383;
      int dxo = (pk >> 14) & 1;
      int lin10 = lin00 + ((pk >> 15) << 7);
      half4v v00 = *(const half4v*)(vbase + ((size_t)lin00 << 6));
      half4v v01 = *(const half4v*)(vbase + ((size_t)(lin00 + dxo) << 6));
      half4v v10 = *(const half4v*)(vbase + ((size_t)lin10 << 6));
      half4v v11 = *(const half4v*)(vbase + ((size_t)(lin10 + dxo) << 6));
      fma4s(acc, w4.x, h2f(v00));
      fma4s(acc, w4.y, h2f(v01));
      fma4s(acc, w4.z, h2f(v10));
      fma4s(acc, w4.w, h2f(v11));
    }
    *(half4v*)(cbase + ((size_t)row << 6)) = f2h(acc);
  }
}

// ---- K3b: output GEMM + halves-avg + BN + ReLU. 64 out-rows/block ----
__global__ __launch_bounds__(256) void gemmbn_kernel(
    const fp16* __restrict__ core, const float* __restrict__ op_w,
    const float* __restrict__ op_b, const float* __restrict__ bn_g,
    const float* __restrict__ bn_b, const float* __restrict__ bn_m,
    const float* __restrict__ bn_v, float* __restrict__ out) {
  __shared__ __align__(16) float Ws[64][68];     // 17.4 KB
  __shared__ __align__(16) fp16 csL[64][72];     // 9.2 KB
  __shared__ __align__(16) fp16 csH[64][72];     // 9.2 KB
  int tid = threadIdx.x;
  int bid = blockIdx.x;
  int logical = (bid & 7) * 128 + (bid >> 3);    // XCD pinning
  int b = logical >> 7;
  int p0 = (logical & 127) * 64;                 // 0..8128
  size_t q0lo = (size_t)b * 16384 + p0;

#pragma unroll
  for (int i0 = 0; i0 < 4096; i0 += 1024) {
    int i = i0 + tid * 4;
    int c = i >> 6, k = i & 63;
    float4 wv = *(const float4*)(op_w + i);
    Ws[k][c] = wv.x; Ws[k + 1][c] = wv.y; Ws[k + 2][c] = wv.z; Ws[k + 3][c] = wv.w;
  }
  // stage 64 low + 64 high core rows (fp16), 16B per load
#pragma unroll
  for (int j0 = 0; j0 < 512; j0 += 256) {
    int j = j0 + tid;
    int r = j >> 3;
    int cc = (j & 7) * 8;
    *(half8v*)&csL[r][cc] = *(const half8v*)(core + (q0lo + r) * 64 + cc);
    *(half8v*)&csH[r][cc] = *(const half8v*)(core + (q0lo + 8192 + r) * 64 + cc);
  }
  __syncthreads();

  int ty = tid >> 4, tx = tid & 15;
  int c0 = tx * 4;
  float4 accL[4], accH[4];
#pragma unroll
  for (int m = 0; m < 4; ++m) {
    accL[m] = make_float4(0.f, 0.f, 0.f, 0.f);
    accH[m] = make_float4(0.f, 0.f, 0.f, 0.f);
  }
#pragma unroll 2
  for (int k0 = 0; k0 < 64; k0 += 4) {
    float4 w0 = *(const float4*)&Ws[k0][c0];
    float4 w1 = *(const float4*)&Ws[k0 + 1][c0];
    float4 w2 = *(const float4*)&Ws[k0 + 2][c0];
    float4 w3 = *(const float4*)&Ws[k0 + 3][c0];
#pragma unroll
    for (int m = 0; m < 4; ++m) {
      int r = ty + 16 * m;
      float4 aL = h2f(*(const half4v*)&csL[r][k0]);
      float4 aH = h2f(*(const half4v*)&csH[r][k0]);
      fma4s(accL[m], aL.x, w0); fma4s(accL[m], aL.y, w1);
      fma4s(accL[m], aL.z, w2); fma4s(accL[m], aL.w, w3);
      fma4s(accH[m], aH.x, w0); fma4s(accH[m], aH.y, w1);
      fma4s(accH[m], aH.z, w2); fma4s(accH[m], aH.w, w3);
    }
  }
  float4 bias4 = *(const float4*)(op_b + c0);
#pragma unroll
  for (int m = 0; m < 4; ++m) {
    int r = ty + 16 * m;
    int f = (p0 + r) * 64 + c0;          // within-batch z-flat position
    int c2 = f >> 14;
    float scale = bn_g[c2] * rsqrtf(bn_v[c2] + 1e-5f);
    float shift = bn_b[c2] - bn_m[c2] * scale;
    float4 z;
    z.x = fmaxf((0.5f * (accL[m].x + accH[m].x) + bias4.x) * scale + shift, 0.f);
    z.y = fmaxf((0.5f * (accL[m].y + accH[m].y) + bias4.y) * scale + shift, 0.f);
    z.z = fmaxf((0.5f * (accL[m].z + accH[m].z) + bias4.z) * scale + shift, 0.f);
    z.w = fmaxf((0.5f * (accL[m].w + accH[m].w) + bias4.w) * scale + shift, 0.f);
    *(float4*)(out + (size_t)b * 524288 + f) = z;
  }
}

extern "C" void kernel_launch(void* const* d_in, const int* in_sizes, int n_in,
                              void* d_out, int out_size, void* d_ws, size_t ws_size,
                              hipStream_t stream) {
  const float* x    = (const float*)d_in[0];
  const float* vp_w = (const float*)d_in[1];
  const float* vp_b = (const float*)d_in[2];
  const float* dw_w = (const float*)d_in[3];
  const float* dw_b = (const float*)d_in[4];
  const float* om_w = (const float*)d_in[5];
  const float* om_b = (const float*)d_in[6];
  const float* op_w = (const float*)d_in[7];
  const float* op_b = (const float*)d_in[8];
  const float* bn_g = (const float*)d_in[9];
  const float* bn_b = (const float*)d_in[10];
  const float* bn_m = (const float*)d_in[11];
  const float* bn_v = (const float*)d_in[12];

  fp16* val_h  = (fp16*)d_ws;                           // 16 MB
  fp16* core_h = (fp16*)((char*)d_ws + (16u << 20));    // 16 MB
  fp16* om_h   = (fp16*)((char*)d_ws + (32u << 20));    // 13.5 MB

  gemm_val_kernel<<<dim3(1024), dim3(256), 0, stream>>>(x, vp_w, vp_b, val_h);
  dwom_kernel<<<dim3(1024), dim3(256), 0, stream>>>(x, dw_w, dw_b, om_w, om_b, om_h);
  gather_kernel<<<dim3(2048), dim3(256), 0, stream>>>(val_h, om_h, core_h);
  gemmbn_kernel<<<dim3(1024), dim3(256), 0, stream>>>(
      core_h, op_w, op_b, bn_g, bn_b, bn_m, bn_v, (float*)d_out);
}